// Round 1
// baseline (35.549 us; speedup 1.0000x reference)
//
#include <hip/hip_runtime.h>
#include <hip/hip_bf16.h>

#define B_DIM 64
#define N_TOT 2048
#define M_DIM 64
#define O_DIM 128
#define NT 8   // neurons per block

typedef __bf16 bf16x8 __attribute__((ext_vector_type(8)));
typedef float f32x4 __attribute__((ext_vector_type(4)));

__device__ __forceinline__ unsigned short f2bf(float f) {
    union { float f; unsigned int u; } v;
    v.f = f;
    unsigned int r = v.u + 0x7fffu + ((v.u >> 16) & 1u);  // round-to-nearest-even
    return (unsigned short)(r >> 16);
}

__global__ __launch_bounds__(512, 2) void superlinear_mfma(
    const float* __restrict__ x, const float* __restrict__ w1,
    const float* __restrict__ b1, float* __restrict__ out)
{
    // bf16 W tile, logical layout [nn][o][k] (k innermost), XOR-swizzled. 128 KiB.
    __shared__ unsigned char wlds[NT * O_DIM * M_DIM * 2];

    const int tid  = threadIdx.x;
    const int lane = tid & 63;
    const int wave = tid >> 6;

    // XCD-aware swizzle: 256 blocks / 8 XCDs -> 32 consecutive n-blocks per XCD
    const int bid  = blockIdx.x;
    const int nblk = (bid & 7) * 32 + (bid >> 3);
    const int n0   = nblk * NT;

    // ---- Stage w1[:, :, n0:n0+8] -> LDS bf16 [nn][o][k], swizzled ----
    // unit u = 16 elements: 4 m (mq*4..+3) x 4 n (n4*4..+3) at fixed o.
    // units = 16 * 128 * 2 = 4096 -> 8 iters x 512 threads.
    #pragma unroll
    for (int it = 0; it < 8; ++it) {
        int u  = it * 512 + tid;
        int n4 = u & 1;
        int o  = (u >> 1) & 127;
        int mq = u >> 8;
        int m  = mq * 4;
        const float* gp = w1 + ((size_t)m * O_DIM + o) * N_TOT + n0 + n4 * 4;
        float4 r0 = *(const float4*)(gp);
        float4 r1 = *(const float4*)(gp + (size_t)O_DIM * N_TOT);
        float4 r2 = *(const float4*)(gp + (size_t)2 * O_DIM * N_TOT);
        float4 r3 = *(const float4*)(gp + (size_t)3 * O_DIM * N_TOT);
        const float* a0 = (const float*)&r0;
        const float* a1 = (const float*)&r1;
        const float* a2 = (const float*)&r2;
        const float* a3 = (const float*)&r3;
        #pragma unroll
        for (int j = 0; j < 4; ++j) {
            int nn = n4 * 4 + j;
            unsigned short e0 = f2bf(a0[j]);
            unsigned short e1 = f2bf(a1[j]);
            unsigned short e2 = f2bf(a2[j]);
            unsigned short e3 = f2bf(a3[j]);
            unsigned long long pk =
                (unsigned long long)e0 | ((unsigned long long)e1 << 16) |
                ((unsigned long long)e2 << 32) | ((unsigned long long)e3 << 48);
            unsigned addr = (unsigned)(nn * (O_DIM * M_DIM * 2) + o * (M_DIM * 2) + m * 2);
            addr ^= (unsigned)((o & 7) << 4);   // bank swizzle (bits 4-6)
            *(unsigned long long*)(wlds + addr) = pk;
        }
    }
    __syncthreads();

    // ---- Each wave computes one neuron's 64x128 output ----
    const int nn  = wave;
    const int n   = n0 + nn;
    const int col = lane & 15;   // o within 16-tile; also b-row for A operand
    const int kg  = lane >> 4;   // k-group

    f32x4 acc[4][8];
    #pragma unroll
    for (int ot = 0; ot < 8; ++ot) {
        float bv = b1[(size_t)n * O_DIM + ot * 16 + col];
        #pragma unroll
        for (int bt = 0; bt < 4; ++bt) {
            acc[bt][ot][0] = bv; acc[bt][ot][1] = bv;
            acc[bt][ot][2] = bv; acc[bt][ot][3] = bv;
        }
    }

    #pragma unroll
    for (int kc = 0; kc < 2; ++kc) {
        // A fragments: x rows, 8 consecutive m per lane, direct from global
        bf16x8 af[4];
        #pragma unroll
        for (int bt = 0; bt < 4; ++bt) {
            int b = bt * 16 + col;
            const float* xp = x + ((size_t)b * N_TOT + n) * M_DIM + kc * 32 + kg * 8;
            float4 lo = *(const float4*)xp;
            float4 hi = *(const float4*)(xp + 4);
            const float* lp = (const float*)&lo;
            const float* hp = (const float*)&hi;
            union { bf16x8 v; unsigned short s[8]; } cvt;
            #pragma unroll
            for (int j = 0; j < 4; ++j) { cvt.s[j] = f2bf(lp[j]); cvt.s[4 + j] = f2bf(hp[j]); }
            af[bt] = cvt.v;
        }
        // B fragments from LDS (ds_read_b128) + 4 MFMAs each
        #pragma unroll
        for (int ot = 0; ot < 8; ++ot) {
            unsigned addr = (unsigned)(nn * 16384 + (ot * 16 + col) * 128 + kc * 64 + kg * 16);
            addr ^= (unsigned)((col & 7) << 4);
            bf16x8 bfrag = *(const bf16x8*)(wlds + addr);
            #pragma unroll
            for (int bt = 0; bt < 4; ++bt)
                acc[bt][ot] = __builtin_amdgcn_mfma_f32_16x16x32_bf16(af[bt], bfrag, acc[bt][ot], 0, 0, 0);
        }
    }

    // ---- Store: D row = kg*4 + r, col = col; coalesced 16-lane x 64B segments ----
    #pragma unroll
    for (int bt = 0; bt < 4; ++bt) {
        #pragma unroll
        for (int r = 0; r < 4; ++r) {
            int b = bt * 16 + kg * 4 + r;
            float* op = out + ((size_t)b * N_TOT + n) * O_DIM + col;
            #pragma unroll
            for (int ot = 0; ot < 8; ++ot)
                op[ot * 16] = acc[bt][ot][r];
        }
    }
}

extern "C" void kernel_launch(void* const* d_in, const int* in_sizes, int n_in,
                              void* d_out, int out_size, void* d_ws, size_t ws_size,
                              hipStream_t stream) {
    const float* x  = (const float*)d_in[0];
    const float* w1 = (const float*)d_in[1];
    const float* b1 = (const float*)d_in[2];
    float* out = (float*)d_out;
    superlinear_mfma<<<dim3(256), dim3(512), 0, stream>>>(x, w1, b1, out);
}